// Round 1
// 12960.739 us; speedup vs baseline: 1.8465x; 1.8465x over previous
//
#include <hip/hip_runtime.h>
#include <hip/hip_bf16.h>
#include <math.h>

using bf16 = __hip_bfloat16;
typedef __attribute__((ext_vector_type(8))) short short8;
typedef __attribute__((ext_vector_type(4))) float f32x4;

#define EMB 768
#define NH 12
#define SEQ 512
#define BB 4
#define NL 12
#define FF 3072
#define VOC 50257
#define NTOK (BB*SEQ)

__device__ __forceinline__ float b2f(bf16 x) { return __bfloat162float(x); }
__device__ __forceinline__ bf16 f2b(float x) { return __float2bfloat16(x); }

// Load element i of an external float tensor whose dtype (f32 vs bf16) is known only at runtime.
__device__ __forceinline__ float ldf(const void* p, size_t i, int f32) {
  if (f32) return ((const float*)p)[i];
  return b2f(((const bf16*)p)[i]);
}

// async 16B global->LDS (wave-uniform LDS base + lane*16)
__device__ __forceinline__ void gload16(const void* g, void* l) {
  __builtin_amdgcn_global_load_lds((const __attribute__((address_space(1))) void*)g,
                                   (__attribute__((address_space(3))) void*)l, 16, 0, 0);
}

// ---------------- dtype detect: ln1_g is all-ones. bf16 pair = 0x3F803F80, f32 = 0x3F800000 ----------------
__global__ void detect_kernel(const unsigned* __restrict__ w, int* __restrict__ flag) {
  if (threadIdx.x == 0) flag[0] = (w[0] == 0x3F803F80u) ? 0 : 1;
}

// ---------------- weight-norm row scales: scale[row] = g[row]/||v[row,:]|| ----------------
__global__ __launch_bounds__(64)
void wn_scale_kernel(const void* __restrict__ v, const void* __restrict__ g,
                     float* __restrict__ scale, int rowlen, const int* __restrict__ dflag) {
  int f32 = *dflag;
  int row = blockIdx.x;
  int lane = threadIdx.x;
  size_t base = (size_t)row * rowlen;
  float s = 0.f;
  for (int j = lane; j < rowlen; j += 64) { float x = ldf(v, base + j, f32); s += x * x; }
  for (int off = 32; off; off >>= 1) s += __shfl_down(s, off);
  if (lane == 0) scale[row] = ldf(g, row, f32) / sqrtf(s);
}

// ---------------- transpose + cast + optional per-k scale: Wt[n][k] = W[k][n] * scale[k] ----------------
__global__ __launch_bounds__(256)
void convT_kernel(const void* __restrict__ W, size_t woff, const float* __restrict__ scale,
                  bf16* __restrict__ Wt, int K, int N, const int* __restrict__ dflag) {
  int f32 = *dflag;
  __shared__ float tile[32][33];
  int k0 = blockIdx.y * 32, n0 = blockIdx.x * 32;
  int tx = threadIdx.x & 31, ty = threadIdx.x >> 5;   // 8 rows per pass
  #pragma unroll
  for (int i = 0; i < 32; i += 8) {
    int k = k0 + ty + i, n = n0 + tx;
    float v = 0.f;
    if (n < N) v = ldf(W, woff + (size_t)k * N + n, f32);
    if (scale) v *= scale[k];
    tile[ty + i][tx] = v;
  }
  __syncthreads();
  #pragma unroll
  for (int i = 0; i < 32; i += 8) {
    int n = n0 + ty + i, k = k0 + tx;
    if (n < N) Wt[(size_t)n * K + k] = f2b(tile[tx][ty + i]);
  }
}

// ---------------- per-batch conditioning vector ----------------
__global__ __launch_bounds__(EMB)
void cond_kernel(const int* __restrict__ eid, const int* __restrict__ cid, const int* __restrict__ pid,
                 const void* __restrict__ emo_emb, const void* __restrict__ ctx_emb, const void* __restrict__ pers_emb,
                 const void* __restrict__ W_emo, const void* __restrict__ b_emo,
                 const void* __restrict__ W_ctx, const void* __restrict__ b_ctx,
                 const void* __restrict__ W_pers, const void* __restrict__ b_pers,
                 float* __restrict__ cond, const int* __restrict__ dflag) {
  int f32 = *dflag;
  int b = blockIdx.x, e = threadIdx.x;
  float acc = ldf(b_emo, e, f32) + ldf(b_ctx, e, f32) + ldf(b_pers, e, f32);
  size_t eb = (size_t)eid[b] * 64;
  for (int i = 0; i < 64; ++i)  acc += ldf(emo_emb, eb + i, f32) * ldf(W_emo, (size_t)i * EMB + e, f32);
  size_t cb = (size_t)cid[b] * 128;
  for (int i = 0; i < 128; ++i) acc += ldf(ctx_emb, cb + i, f32) * ldf(W_ctx, (size_t)i * EMB + e, f32);
  size_t pb = (size_t)pid[b] * 96;
  for (int i = 0; i < 96; ++i)  acc += ldf(pers_emb, pb + i, f32) * ldf(W_pers, (size_t)i * EMB + e, f32);
  cond[b * EMB + e] = acc;
}

// ---------------- token embedding + conditioning ----------------
__global__ __launch_bounds__(256)
void embed_kernel(const int* __restrict__ ids, const int* __restrict__ pos,
                  const void* __restrict__ wte, const void* __restrict__ wpe,
                  const float* __restrict__ cond, float* __restrict__ h,
                  const int* __restrict__ dflag) {
  int f32 = *dflag;
  int idx = blockIdx.x * 256 + threadIdx.x;   // < NTOK*EMB
  int e = idx % EMB;
  int t = idx / EMB;
  int b = t / SEQ;
  h[idx] = ldf(wte, (size_t)ids[t] * EMB + e, f32) + ldf(wpe, (size_t)pos[t] * EMB + e, f32) + cond[b * EMB + e];
}

// ---------------- layernorm: f32 h -> bf16 x.  g/b external, element offset `goff` ----------------
__global__ __launch_bounds__(256)
void ln_kernel(const float* __restrict__ h, const void* __restrict__ g, const void* __restrict__ b,
               size_t goff, bf16* __restrict__ out, const int* __restrict__ dflag) {
  int f32 = *dflag;
  __shared__ float r1[256], r2[256];
  int row = blockIdx.x, tid = threadIdx.x;
  const float* hr = h + (size_t)row * EMB;
  float vals[3];
  float s = 0.f, ss = 0.f;
  #pragma unroll
  for (int i = 0; i < 3; ++i) { float x = hr[tid + i * 256]; vals[i] = x; s += x; ss += x * x; }
  r1[tid] = s; r2[tid] = ss; __syncthreads();
  for (int off = 128; off; off >>= 1) {
    if (tid < off) { r1[tid] += r1[tid + off]; r2[tid] += r2[tid + off]; }
    __syncthreads();
  }
  float mean = r1[0] * (1.f / EMB);
  float var  = r2[0] * (1.f / EMB) - mean * mean;
  float rstd = rsqrtf(var + 1e-5f);
  #pragma unroll
  for (int i = 0; i < 3; ++i) {
    int c = tid + i * 256;
    out[(size_t)row * EMB + c] = f2b((vals[i] - mean) * rstd * ldf(g, goff + c, f32) + ldf(b, goff + c, f32));
  }
}

// ---------------- GEMM: C[M,N] = A[M,K](bf16) @ Bt[N,K](bf16, pre-transposed/scaled) + bias ----------------
// m97 structure: 128x128 tile, BK=32, 4 waves (2x2), each wave 64x64 via 4x4 16x16x32 MFMA frags,
// global_load_lds(16B) staging, 2-barrier K-loop, grouped pid mapping for L2 reuse.
enum { EPI_OUT = 0, EPI_F32 = 1, EPI_GELU = 2, EPI_ADD = 3 };

template<int EPI>
__global__ __launch_bounds__(256)
void gemm128_kernel(const bf16* __restrict__ A, const bf16* __restrict__ Bt,
                    const void* __restrict__ bias, size_t biasoff,
                    void* __restrict__ C, int M, int N, int K,
                    int num_n, int num_m, const int* __restrict__ dflag) {
  int f32 = *dflag;
  __shared__ bf16 As[128 * 32];
  __shared__ bf16 Bs[128 * 32];
  int tid = threadIdx.x;
  int wv = tid >> 6, lane = tid & 63;

  // grouped block mapping: GROUP_M m-panels share B panels in L2
  const int GROUP_M = 8;
  int pid = blockIdx.x;
  int width = GROUP_M * num_n;
  int gid = pid / width;
  int first_m = gid * GROUP_M;
  int gsz = num_m - first_m; if (gsz > GROUP_M) gsz = GROUP_M;
  int m_idx = first_m + (pid % width) % gsz;
  int n_idx = (pid % width) / gsz;
  int m0 = m_idx * 128, n0 = n_idx * 128;

  int quad = lane >> 4, r = lane & 15;
  int wm = (wv >> 1) * 64, wn = (wv & 1) * 64;
  f32x4 acc[4][4] = {};

  // staging: per instr, 64 lanes x 16B cover 16 rows x 32 k (linear LDS order)
  int srow = lane >> 2;          // 0..15
  int sk   = (lane & 3) * 8;     // k-octet start
  int arow0 = m0 + wv * 32 + srow;   // wave's 2 chunks: rows wv*32 .. wv*32+31
  int brow0 = n0 + wv * 32 + srow;

  for (int k0 = 0; k0 < K; k0 += 32) {
    #pragma unroll
    for (int ii = 0; ii < 2; ++ii) {
      int ar = arow0 + ii * 16;
      gload16(A + (size_t)ar * K + k0 + sk, As + (wv * 2 + ii) * 16 * 32);
      int br = brow0 + ii * 16; if (br > N - 1) br = N - 1;   // clamp (reads masked at store)
      gload16(Bt + (size_t)br * K + k0 + sk, Bs + (wv * 2 + ii) * 16 * 32);
    }
    __syncthreads();   // drains vmcnt before any wave reads LDS
    short8 af[4], bfr[4];
    #pragma unroll
    for (int i = 0; i < 4; ++i) af[i]  = *reinterpret_cast<const short8*>(&As[(wm + i * 16 + r) * 32 + quad * 8]);
    #pragma unroll
    for (int j = 0; j < 4; ++j) bfr[j] = *reinterpret_cast<const short8*>(&Bs[(wn + j * 16 + r) * 32 + quad * 8]);
    #pragma unroll
    for (int i = 0; i < 4; ++i)
      #pragma unroll
      for (int j = 0; j < 4; ++j)
        acc[i][j] = __builtin_amdgcn_mfma_f32_16x16x32_bf16(af[i], bfr[j], acc[i][j], 0, 0, 0);
    __syncthreads();   // protect LDS from next-iter staging
  }

  #pragma unroll
  for (int i = 0; i < 4; ++i)
    #pragma unroll
    for (int j = 0; j < 4; ++j)
      #pragma unroll
      for (int reg = 0; reg < 4; ++reg) {
        int gm = m0 + wm + i * 16 + quad * 4 + reg;
        int gn = n0 + wn + j * 16 + r;
        if (gn >= N) continue;
        float v = acc[i][j][reg];
        if (bias) v += ldf(bias, biasoff + gn, f32);
        if (EPI == EPI_GELU) v = 0.5f * v * (1.f + erff(v * 0.7071067811865475f));
        size_t idx = (size_t)gm * N + gn;
        if (EPI == EPI_ADD)       ((float*)C)[idx] += v;
        else if (EPI == EPI_F32)  ((float*)C)[idx] = v;
        else if (EPI == EPI_GELU) ((bf16*)C)[idx] = f2b(v);
        else {  // EPI_OUT: match harness output dtype
          if (f32) ((float*)C)[idx] = v; else ((bf16*)C)[idx] = f2b(v);
        }
      }
}

// ---------------- attention: one block per (b, h, q) ----------------
__global__ __launch_bounds__(512)
void attn_kernel(const float* __restrict__ qkv, const void* __restrict__ eb, size_t eboff,
                 const void* __restrict__ mask, bf16* __restrict__ o,
                 const int* __restrict__ dflag) {
  int f32 = *dflag;
  __shared__ float qv[64];
  __shared__ float s[512];
  __shared__ float red[512];
  __shared__ float part[8][64];
  int tid = threadIdx.x;
  int q = blockIdx.x, hh = blockIdx.y, b = blockIdx.z;
  const float* qrow = qkv + (size_t)(b * SEQ + q) * 2304 + hh * 64;
  if (tid < 64) qv[tid] = qrow[tid];
  __syncthreads();
  const float* krow = qkv + (size_t)(b * SEQ + tid) * 2304 + 768 + hh * 64;
  float acc = 0.f;
  #pragma unroll 8
  for (int d = 0; d < 64; ++d) acc += qv[d] * krow[d];
  float sc = acc * 0.125f + ldf(eb, eboff + hh, f32) + ldf(mask, (size_t)b * SEQ + tid, f32);
  s[tid] = sc; red[tid] = sc;
  __syncthreads();
  for (int off = 256; off; off >>= 1) { if (tid < off) red[tid] = fmaxf(red[tid], red[tid + off]); __syncthreads(); }
  float mx = red[0];
  __syncthreads();
  float e = expf(sc - mx);
  s[tid] = e; red[tid] = e;
  __syncthreads();
  for (int off = 256; off; off >>= 1) { if (tid < off) red[tid] += red[tid + off]; __syncthreads(); }
  float l = red[0];
  int g = tid >> 6, d = tid & 63;
  const float* vbase = qkv + (size_t)(b * SEQ) * 2304 + 1536 + hh * 64 + d;
  float pa = 0.f;
  for (int t = g * 64; t < g * 64 + 64; ++t) pa += s[t] * vbase[(size_t)t * 2304];
  part[g][d] = pa;
  __syncthreads();
  if (tid < 64) {
    float oo = 0.f;
    #pragma unroll
    for (int gg = 0; gg < 8; ++gg) oo += part[gg][tid];
    o[(size_t)(b * SEQ + q) * EMB + hh * 64 + tid] = f2b(oo / l);
  }
}

// ---------------- host ----------------
extern "C" void kernel_launch(void* const* d_in, const int* in_sizes, int n_in,
                              void* d_out, int out_size, void* d_ws, size_t ws_size,
                              hipStream_t stream) {
  const int* input_ids       = (const int*)d_in[0];
  const int* position_ids    = (const int*)d_in[1];
  const int* emotion_ids     = (const int*)d_in[2];
  const int* context_ids     = (const int*)d_in[3];
  const int* personality_ids = (const int*)d_in[4];
  const void* mask    = d_in[5];
  const void* wte     = d_in[6];
  const void* wpe     = d_in[7];
  const void* emo_emb = d_in[8];
  const void* ctx_emb = d_in[9];
  const void* pers_emb= d_in[10];
  const void* W_emo   = d_in[11];
  const void* b_emo   = d_in[12];
  const void* W_ctx   = d_in[13];
  const void* b_ctx   = d_in[14];
  const void* W_pers  = d_in[15];
  const void* b_pers  = d_in[16];
  const void* ln1_g   = d_in[17];
  const void* ln1_b   = d_in[18];
  const void* W_qkv   = d_in[19];
  const void* b_qkv   = d_in[20];
  const void* attn_v  = d_in[21];
  const void* attn_g  = d_in[22];
  const void* attn_b  = d_in[23];
  const void* emo_bias= d_in[24];
  const void* ln2_g   = d_in[25];
  const void* ln2_b   = d_in[26];
  const void* W_fc    = d_in[27];
  const void* b_fc    = d_in[28];
  const void* mlp_v   = d_in[29];
  const void* mlp_g   = d_in[30];
  const void* mlp_b   = d_in[31];
  const void* ln_f_g  = d_in[32];
  const void* ln_f_b  = d_in[33];
  const void* W_lm    = d_in[34];

  // workspace carve
  char* p = (char*)d_ws;
  auto alloc = [&](size_t bytes) { char* r = p; p += (bytes + 255) & ~(size_t)255; return r; };
  float* h      = (float*)alloc((size_t)NTOK * EMB * 4);
  bf16*  x_bf   = (bf16*) alloc((size_t)NTOK * EMB * 2);
  float* qkv    = (float*)alloc((size_t)NTOK * 3 * EMB * 4);
  bf16*  o_bf   = (bf16*) alloc((size_t)NTOK * EMB * 2);
  bf16*  act_bf = (bf16*) alloc((size_t)NTOK * FF * 2);
  float* cond   = (float*)alloc((size_t)BB * EMB * 4);
  float* sc_att = (float*)alloc((size_t)NL * EMB * 4);
  float* sc_mlp = (float*)alloc((size_t)NL * FF * 4);
  int*   dflag  = (int*)  alloc(256);
  bf16*  Wt_qkv = (bf16*) alloc((size_t)(3 * EMB) * EMB * 2);   // [2304][768]
  bf16*  Wt_att = (bf16*) alloc((size_t)EMB * EMB * 2);         // [768][768]
  bf16*  Wt_fc  = (bf16*) alloc((size_t)FF * EMB * 2);          // [3072][768]
  bf16*  Wt_mlp = (bf16*) alloc((size_t)EMB * FF * 2);          // [768][3072]
  bf16*  Wt_lm  = (bf16*) alloc((size_t)VOC * EMB * 2);         // [50257][768]

  // dtype detect (ln1_g is all-ones in either dtype)
  detect_kernel<<<1, 64, 0, stream>>>((const unsigned*)ln1_g, dflag);

  // precompute
  wn_scale_kernel<<<NL * EMB, 64, 0, stream>>>(attn_v, attn_g, sc_att, EMB, dflag);
  wn_scale_kernel<<<NL * FF,  64, 0, stream>>>(mlp_v,  mlp_g,  sc_mlp, EMB, dflag);
  cond_kernel<<<BB, EMB, 0, stream>>>(emotion_ids, context_ids, personality_ids,
                                      emo_emb, ctx_emb, pers_emb,
                                      W_emo, b_emo, W_ctx, b_ctx, W_pers, b_pers, cond, dflag);
  embed_kernel<<<(NTOK * EMB) / 256, 256, 0, stream>>>(input_ids, position_ids, wte, wpe, cond, h, dflag);

  // LM head weight: transpose+cast once per launch
  convT_kernel<<<dim3((VOC + 31) / 32, EMB / 32), 256, 0, stream>>>(
      W_lm, 0, nullptr, Wt_lm, EMB, VOC, dflag);

  const int num_m = NTOK / 128;   // 16
  for (int l = 0; l < NL; ++l) {
    size_t off_E   = (size_t)l * EMB;
    size_t off_3E  = (size_t)l * 3 * EMB;
    size_t off_EE  = (size_t)l * EMB * EMB;
    size_t off_E3E = (size_t)l * EMB * 3 * EMB;
    size_t off_EI  = (size_t)l * EMB * FF;
    size_t off_I   = (size_t)l * FF;
    size_t off_IE  = (size_t)l * FF * EMB;
    size_t off_H   = (size_t)l * NH;

    // per-layer weight convert (transpose to [N][K] bf16; fold wn scale for attn/mlp proj)
    convT_kernel<<<dim3((3 * EMB) / 32, EMB / 32), 256, 0, stream>>>(
        W_qkv, off_E3E, nullptr, Wt_qkv, EMB, 3 * EMB, dflag);
    convT_kernel<<<dim3(EMB / 32, EMB / 32), 256, 0, stream>>>(
        attn_v, off_EE, sc_att + l * EMB, Wt_att, EMB, EMB, dflag);
    convT_kernel<<<dim3(FF / 32, EMB / 32), 256, 0, stream>>>(
        W_fc, off_EI, nullptr, Wt_fc, EMB, FF, dflag);
    convT_kernel<<<dim3(EMB / 32, FF / 32), 256, 0, stream>>>(
        mlp_v, off_IE, sc_mlp + l * FF, Wt_mlp, FF, EMB, dflag);

    ln_kernel<<<NTOK, 256, 0, stream>>>(h, ln1_g, ln1_b, off_E, x_bf, dflag);
    gemm128_kernel<EPI_F32><<<num_m * 18, 256, 0, stream>>>(
        x_bf, Wt_qkv, b_qkv, off_3E, qkv, NTOK, 3 * EMB, EMB, 18, num_m, dflag);
    attn_kernel<<<dim3(SEQ, NH, BB), 512, 0, stream>>>(qkv, emo_bias, off_H, mask, o_bf, dflag);
    gemm128_kernel<EPI_ADD><<<num_m * 6, 256, 0, stream>>>(
        o_bf, Wt_att, attn_b, off_E, h, NTOK, EMB, EMB, 6, num_m, dflag);
    ln_kernel<<<NTOK, 256, 0, stream>>>(h, ln2_g, ln2_b, off_E, x_bf, dflag);
    gemm128_kernel<EPI_GELU><<<num_m * 24, 256, 0, stream>>>(
        x_bf, Wt_fc, b_fc, off_I, act_bf, NTOK, FF, EMB, 24, num_m, dflag);
    gemm128_kernel<EPI_ADD><<<num_m * 6, 256, 0, stream>>>(
        act_bf, Wt_mlp, mlp_b, off_E, h, NTOK, EMB, FF, 6, num_m, dflag);
  }

  ln_kernel<<<NTOK, 256, 0, stream>>>(h, ln_f_g, ln_f_b, 0, x_bf, dflag);
  const int lm_nn = (VOC + 127) / 128;   // 393
  gemm128_kernel<EPI_OUT><<<num_m * lm_nn, 256, 0, stream>>>(
      x_bf, Wt_lm, nullptr, 0, d_out, NTOK, VOC, EMB, lm_nn, num_m, dflag);
}

// Round 2
// 4541.032 us; speedup vs baseline: 5.2701x; 2.8541x over previous
//
#include <hip/hip_runtime.h>
#include <hip/hip_bf16.h>
#include <math.h>

using bf16 = __hip_bfloat16;
typedef __attribute__((ext_vector_type(8))) short short8;
typedef __attribute__((ext_vector_type(4))) float f32x4;

#define EMB 768
#define NH 12
#define SEQ 512
#define BB 4
#define NL 12
#define FF 3072
#define VOC 50257
#define NTOK (BB*SEQ)

__device__ __forceinline__ float b2f(bf16 x) { return __bfloat162float(x); }
__device__ __forceinline__ bf16 f2b(float x) { return __float2bfloat16(x); }

// Load element i of an external float tensor whose dtype (f32 vs bf16) is known only at runtime.
__device__ __forceinline__ float ldf(const void* p, size_t i, int f32) {
  if (f32) return ((const float*)p)[i];
  return b2f(((const bf16*)p)[i]);
}

// async 16B global->LDS (wave-uniform LDS base + lane*16)
__device__ __forceinline__ void gload16(const void* g, void* l) {
  __builtin_amdgcn_global_load_lds((const __attribute__((address_space(1))) void*)g,
                                   (__attribute__((address_space(3))) void*)l, 16, 0, 0);
}

// ---------------- dtype detect: ln1_g is all-ones. bf16 pair = 0x3F803F80, f32 = 0x3F800000 ----------------
__global__ void detect_kernel(const unsigned* __restrict__ w, int* __restrict__ flag) {
  if (threadIdx.x == 0) flag[0] = (w[0] == 0x3F803F80u) ? 0 : 1;
}

// ---------------- weight-norm row scales: scale[row] = g[row]/||v[row,:]|| ----------------
__global__ __launch_bounds__(64)
void wn_scale_kernel(const void* __restrict__ v, const void* __restrict__ g,
                     float* __restrict__ scale, int rowlen, const int* __restrict__ dflag) {
  int f32 = *dflag;
  int row = blockIdx.x;
  int lane = threadIdx.x;
  size_t base = (size_t)row * rowlen;
  float s = 0.f;
  for (int j = lane; j < rowlen; j += 64) { float x = ldf(v, base + j, f32); s += x * x; }
  for (int off = 32; off; off >>= 1) s += __shfl_down(s, off);
  if (lane == 0) scale[row] = ldf(g, row, f32) / sqrtf(s);
}

// ---------------- transpose + cast + optional per-k scale: Wt[n][k] = W[k][n] * scale[k] ----------------
__global__ __launch_bounds__(256)
void convT_kernel(const void* __restrict__ W, size_t woff, const float* __restrict__ scale,
                  bf16* __restrict__ Wt, int K, int N, const int* __restrict__ dflag) {
  int f32 = *dflag;
  __shared__ float tile[32][33];
  int k0 = blockIdx.y * 32, n0 = blockIdx.x * 32;
  int tx = threadIdx.x & 31, ty = threadIdx.x >> 5;   // 8 rows per pass
  #pragma unroll
  for (int i = 0; i < 32; i += 8) {
    int k = k0 + ty + i, n = n0 + tx;
    float v = 0.f;
    if (n < N) v = ldf(W, woff + (size_t)k * N + n, f32);
    if (scale) v *= scale[k];
    tile[ty + i][tx] = v;
  }
  __syncthreads();
  #pragma unroll
  for (int i = 0; i < 32; i += 8) {
    int n = n0 + ty + i, k = k0 + tx;
    if (n < N) Wt[(size_t)n * K + k] = f2b(tile[tx][ty + i]);
  }
}

// ---------------- per-batch conditioning vector ----------------
__global__ __launch_bounds__(EMB)
void cond_kernel(const int* __restrict__ eid, const int* __restrict__ cid, const int* __restrict__ pid,
                 const void* __restrict__ emo_emb, const void* __restrict__ ctx_emb, const void* __restrict__ pers_emb,
                 const void* __restrict__ W_emo, const void* __restrict__ b_emo,
                 const void* __restrict__ W_ctx, const void* __restrict__ b_ctx,
                 const void* __restrict__ W_pers, const void* __restrict__ b_pers,
                 float* __restrict__ cond, const int* __restrict__ dflag) {
  int f32 = *dflag;
  int b = blockIdx.x, e = threadIdx.x;
  float acc = ldf(b_emo, e, f32) + ldf(b_ctx, e, f32) + ldf(b_pers, e, f32);
  size_t eb = (size_t)eid[b] * 64;
  for (int i = 0; i < 64; ++i)  acc += ldf(emo_emb, eb + i, f32) * ldf(W_emo, (size_t)i * EMB + e, f32);
  size_t cb = (size_t)cid[b] * 128;
  for (int i = 0; i < 128; ++i) acc += ldf(ctx_emb, cb + i, f32) * ldf(W_ctx, (size_t)i * EMB + e, f32);
  size_t pb = (size_t)pid[b] * 96;
  for (int i = 0; i < 96; ++i)  acc += ldf(pers_emb, pb + i, f32) * ldf(W_pers, (size_t)i * EMB + e, f32);
  cond[b * EMB + e] = acc;
}

// ---------------- token embedding + conditioning ----------------
__global__ __launch_bounds__(256)
void embed_kernel(const int* __restrict__ ids, const int* __restrict__ pos,
                  const void* __restrict__ wte, const void* __restrict__ wpe,
                  const float* __restrict__ cond, float* __restrict__ h,
                  const int* __restrict__ dflag) {
  int f32 = *dflag;
  int idx = blockIdx.x * 256 + threadIdx.x;   // < NTOK*EMB
  int e = idx % EMB;
  int t = idx / EMB;
  int b = t / SEQ;
  h[idx] = ldf(wte, (size_t)ids[t] * EMB + e, f32) + ldf(wpe, (size_t)pos[t] * EMB + e, f32) + cond[b * EMB + e];
}

// ---------------- layernorm: f32 h -> bf16 x.  g/b external, element offset `goff` ----------------
__global__ __launch_bounds__(256)
void ln_kernel(const float* __restrict__ h, const void* __restrict__ g, const void* __restrict__ b,
               size_t goff, bf16* __restrict__ out, const int* __restrict__ dflag) {
  int f32 = *dflag;
  __shared__ float r1[256], r2[256];
  int row = blockIdx.x, tid = threadIdx.x;
  const float* hr = h + (size_t)row * EMB;
  float vals[3];
  float s = 0.f, ss = 0.f;
  #pragma unroll
  for (int i = 0; i < 3; ++i) { float x = hr[tid + i * 256]; vals[i] = x; s += x; ss += x * x; }
  r1[tid] = s; r2[tid] = ss; __syncthreads();
  for (int off = 128; off; off >>= 1) {
    if (tid < off) { r1[tid] += r1[tid + off]; r2[tid] += r2[tid + off]; }
    __syncthreads();
  }
  float mean = r1[0] * (1.f / EMB);
  float var  = r2[0] * (1.f / EMB) - mean * mean;
  float rstd = rsqrtf(var + 1e-5f);
  #pragma unroll
  for (int i = 0; i < 3; ++i) {
    int c = tid + i * 256;
    out[(size_t)row * EMB + c] = f2b((vals[i] - mean) * rstd * ldf(g, goff + c, f32) + ldf(b, goff + c, f32));
  }
}

// ---------------- GEMM: C[M,N] = A[M,K](bf16) @ Bt[N,K](bf16, pre-transposed/scaled) + bias ----------------
// m97 structure: 128x128 tile, BK=32, 4 waves (2x2), each wave 64x64 via 4x4 16x16x32 MFMA frags,
// global_load_lds(16B) staging, 2-barrier K-loop, grouped pid mapping for L2 reuse.
enum { EPI_OUT = 0, EPI_F32 = 1, EPI_GELU = 2, EPI_ADD = 3 };

template<int EPI>
__global__ __launch_bounds__(256)
void gemm128_kernel(const bf16* __restrict__ A, const bf16* __restrict__ Bt,
                    const void* __restrict__ bias, size_t biasoff,
                    void* __restrict__ C, int M, int N, int K,
                    int num_n, int num_m, const int* __restrict__ dflag) {
  int f32 = *dflag;
  __shared__ bf16 As[128 * 32];
  __shared__ bf16 Bs[128 * 32];
  int tid = threadIdx.x;
  int wv = tid >> 6, lane = tid & 63;

  // grouped block mapping: GROUP_M m-panels share B panels in L2
  const int GROUP_M = 8;
  int pid = blockIdx.x;
  int width = GROUP_M * num_n;
  int gid = pid / width;
  int first_m = gid * GROUP_M;
  int gsz = num_m - first_m; if (gsz > GROUP_M) gsz = GROUP_M;
  int m_idx = first_m + (pid % width) % gsz;
  int n_idx = (pid % width) / gsz;
  int m0 = m_idx * 128, n0 = n_idx * 128;

  int quad = lane >> 4, r = lane & 15;
  int wm = (wv >> 1) * 64, wn = (wv & 1) * 64;
  f32x4 acc[4][4] = {};

  // staging: per instr, 64 lanes x 16B cover 16 rows x 32 k (linear LDS order)
  int srow = lane >> 2;          // 0..15
  int sk   = (lane & 3) * 8;     // k-octet start
  int arow0 = m0 + wv * 32 + srow;   // wave's 2 chunks: rows wv*32 .. wv*32+31
  int brow0 = n0 + wv * 32 + srow;

  for (int k0 = 0; k0 < K; k0 += 32) {
    #pragma unroll
    for (int ii = 0; ii < 2; ++ii) {
      int ar = arow0 + ii * 16;
      gload16(A + (size_t)ar * K + k0 + sk, As + (wv * 2 + ii) * 16 * 32);
      int br = brow0 + ii * 16; if (br > N - 1) br = N - 1;   // clamp (reads masked at store)
      gload16(Bt + (size_t)br * K + k0 + sk, Bs + (wv * 2 + ii) * 16 * 32);
    }
    __syncthreads();   // drains vmcnt before any wave reads LDS
    short8 af[4], bfr[4];
    #pragma unroll
    for (int i = 0; i < 4; ++i) af[i]  = *reinterpret_cast<const short8*>(&As[(wm + i * 16 + r) * 32 + quad * 8]);
    #pragma unroll
    for (int j = 0; j < 4; ++j) bfr[j] = *reinterpret_cast<const short8*>(&Bs[(wn + j * 16 + r) * 32 + quad * 8]);
    #pragma unroll
    for (int i = 0; i < 4; ++i)
      #pragma unroll
      for (int j = 0; j < 4; ++j)
        acc[i][j] = __builtin_amdgcn_mfma_f32_16x16x32_bf16(af[i], bfr[j], acc[i][j], 0, 0, 0);
    __syncthreads();   // protect LDS from next-iter staging
  }

  #pragma unroll
  for (int i = 0; i < 4; ++i)
    #pragma unroll
    for (int j = 0; j < 4; ++j)
      #pragma unroll
      for (int reg = 0; reg < 4; ++reg) {
        int gm = m0 + wm + i * 16 + quad * 4 + reg;
        int gn = n0 + wn + j * 16 + r;
        if (gn >= N) continue;
        float v = acc[i][j][reg];
        if (bias) v += ldf(bias, biasoff + gn, f32);
        if (EPI == EPI_GELU) v = 0.5f * v * (1.f + erff(v * 0.7071067811865475f));
        size_t idx = (size_t)gm * N + gn;
        if (EPI == EPI_ADD)       ((float*)C)[idx] += v;
        else if (EPI == EPI_F32)  ((float*)C)[idx] = v;
        else if (EPI == EPI_GELU) ((bf16*)C)[idx] = f2b(v);
        else {  // EPI_OUT: match harness output dtype
          if (f32) ((float*)C)[idx] = v; else ((bf16*)C)[idx] = f2b(v);
        }
      }
}

// ---------------- flash attention: one block per (b, h, 64-row q-tile), 4 waves x 16 q-rows ----------------
// MFMA 16x16x32 bf16 throughout. K staged [kr][d] swizzled; V staged transposed [d][kr] swizzled;
// P round-trips LDS (per-wave region) to convert C-layout -> A-layout. Online softmax in registers.
__global__ __launch_bounds__(256)
void fattn_kernel(const float* __restrict__ qkv, const void* __restrict__ eb, size_t eboff,
                  const void* __restrict__ mask, bf16* __restrict__ o,
                  const int* __restrict__ dflag) {
  int f32 = *dflag;
  __shared__ bf16 Kl[64 * 64];
  __shared__ bf16 Vt[64 * 64];
  __shared__ bf16 Pl[4 * 16 * 64];
  int tid = threadIdx.x;
  int w = tid >> 6, l = tid & 63;
  int hl = l & 15, hg = l >> 4;          // half-lane (0..15), group (0..3)
  int qt = blockIdx.x, hh = blockIdx.y, b = blockIdx.z;
  size_t tokbase = (size_t)b * SEQ;

  // Q A-fragments, loaded once; 0.125 scale folded into bf16 cast.
  int qrow = qt * 64 + w * 16 + hl;
  const float* qp = qkv + (tokbase + qrow) * 2304 + hh * 64;
  short8 qa[2];
  #pragma unroll
  for (int s = 0; s < 2; ++s) {
    bf16 tmp[8];
    #pragma unroll
    for (int j = 0; j < 8; ++j) tmp[j] = f2b(qp[s * 32 + hg * 8 + j] * 0.125f);
    qa[s] = *reinterpret_cast<short8*>(tmp);
  }
  float ebv = ldf(eb, eboff + hh, f32);

  float m[4], lsum[4];
  f32x4 oa[4] = {};
  #pragma unroll
  for (int r = 0; r < 4; ++r) { m[r] = -INFINITY; lsum[r] = 0.f; }

  for (int kt = 0; kt < 8; ++kt) {
    int k0 = kt * 64;
    // ---- stage K [kr][d] and V transposed [d][kr], both XOR-swizzled ----
    #pragma unroll
    for (int it = 0; it < 2; ++it) {
      int item = tid + it * 256;          // 0..511
      int kr = item >> 3, oct = item & 7; // tile k-row, d-octet
      const float* kp = qkv + (tokbase + k0 + kr) * 2304 + 768 + hh * 64 + oct * 8;
      bf16 tmp[8];
      #pragma unroll
      for (int j = 0; j < 8; ++j) tmp[j] = f2b(kp[j]);
      *reinterpret_cast<short8*>(&Kl[kr * 64 + ((oct * 8) ^ ((kr & 7) << 3))]) =
          *reinterpret_cast<short8*>(tmp);
      const float* vp = qkv + (tokbase + k0 + kr) * 2304 + 1536 + hh * 64 + oct * 8;
      #pragma unroll
      for (int j = 0; j < 8; ++j) {
        int d = oct * 8 + j;
        Vt[d * 64 + (kr ^ ((d & 7) << 3))] = f2b(vp[j]);
      }
    }
    __syncthreads();

    // ---- S = (Q*0.125) K^T via MFMA: sa[j] covers k-cols j*16..+16 ----
    f32x4 sa[4] = {};
    #pragma unroll
    for (int s = 0; s < 2; ++s)
      #pragma unroll
      for (int j = 0; j < 4; ++j) {
        int n = j * 16 + hl;
        short8 kb = *reinterpret_cast<const short8*>(
            &Kl[n * 64 + ((s * 32 + hg * 8) ^ ((n & 7) << 3))]);
        sa[j] = __builtin_amdgcn_mfma_f32_16x16x32_bf16(qa[s], kb, sa[j], 0, 0, 0);
      }

    // ---- online softmax (per-lane rows hg*4+reg, cols j*16+hl) ----
    float p[4][4];
    float mv[4];
    #pragma unroll
    for (int j = 0; j < 4; ++j) mv[j] = ldf(mask, (size_t)b * SEQ + k0 + j * 16 + hl, f32);
    #pragma unroll
    for (int r = 0; r < 4; ++r) {
      float tm = -INFINITY;
      #pragma unroll
      for (int j = 0; j < 4; ++j) {
        p[j][r] = sa[j][r] + ebv + mv[j];
        tm = fmaxf(tm, p[j][r]);
      }
      #pragma unroll
      for (int off = 1; off < 16; off <<= 1) tm = fmaxf(tm, __shfl_xor(tm, off));
      float mn = fmaxf(m[r], tm);
      float alpha = expf(m[r] - mn);
      float ps = 0.f;
      #pragma unroll
      for (int j = 0; j < 4; ++j) { p[j][r] = expf(p[j][r] - mn); ps += p[j][r]; }
      #pragma unroll
      for (int off = 1; off < 16; off <<= 1) ps += __shfl_xor(ps, off);
      lsum[r] = lsum[r] * alpha + ps;
      m[r] = mn;
      #pragma unroll
      for (int dt = 0; dt < 4; ++dt) oa[dt][r] *= alpha;
    }

    // ---- P -> LDS (per-wave region, swizzled), then PV MFMA ----
    #pragma unroll
    for (int r = 0; r < 4; ++r) {
      int qr = hg * 4 + r;
      #pragma unroll
      for (int j = 0; j < 4; ++j) {
        int c = j * 16 + hl;
        Pl[w * 1024 + qr * 64 + (c ^ ((qr & 7) << 3))] = f2b(p[j][r]);
      }
    }
    #pragma unroll
    for (int s = 0; s < 2; ++s) {
      short8 pa = *reinterpret_cast<const short8*>(
          &Pl[w * 1024 + hl * 64 + ((s * 32 + hg * 8) ^ ((hl & 7) << 3))]);
      #pragma unroll
      for (int dt = 0; dt < 4; ++dt) {
        int d = dt * 16 + hl;
        short8 vb = *reinterpret_cast<const short8*>(
            &Vt[d * 64 + ((s * 32 + hg * 8) ^ ((d & 7) << 3))]);
        oa[dt] = __builtin_amdgcn_mfma_f32_16x16x32_bf16(pa, vb, oa[dt], 0, 0, 0);
      }
    }
    __syncthreads();   // protect Kl/Vt before next tile's staging
  }

  // ---- epilogue: O / lsum -> bf16 ----
  #pragma unroll
  for (int r = 0; r < 4; ++r) {
    float rl = 1.f / lsum[r];
    size_t trow = tokbase + qt * 64 + w * 16 + hg * 4 + r;
    #pragma unroll
    for (int dt = 0; dt < 4; ++dt)
      o[trow * EMB + hh * 64 + dt * 16 + hl] = f2b(oa[dt][r] * rl);
  }
}

// ---------------- host ----------------
extern "C" void kernel_launch(void* const* d_in, const int* in_sizes, int n_in,
                              void* d_out, int out_size, void* d_ws, size_t ws_size,
                              hipStream_t stream) {
  const int* input_ids       = (const int*)d_in[0];
  const int* position_ids    = (const int*)d_in[1];
  const int* emotion_ids     = (const int*)d_in[2];
  const int* context_ids     = (const int*)d_in[3];
  const int* personality_ids = (const int*)d_in[4];
  const void* mask    = d_in[5];
  const void* wte     = d_in[6];
  const void* wpe     = d_in[7];
  const void* emo_emb = d_in[8];
  const void* ctx_emb = d_in[9];
  const void* pers_emb= d_in[10];
  const void* W_emo   = d_in[11];
  const void* b_emo   = d_in[12];
  const void* W_ctx   = d_in[13];
  const void* b_ctx   = d_in[14];
  const void* W_pers  = d_in[15];
  const void* b_pers  = d_in[16];
  const void* ln1_g   = d_in[17];
  const void* ln1_b   = d_in[18];
  const void* W_qkv   = d_in[19];
  const void* b_qkv   = d_in[20];
  const void* attn_v  = d_in[21];
  const void* attn_g  = d_in[22];
  const void* attn_b  = d_in[23];
  const void* emo_bias= d_in[24];
  const void* ln2_g   = d_in[25];
  const void* ln2_b   = d_in[26];
  const void* W_fc    = d_in[27];
  const void* b_fc    = d_in[28];
  const void* mlp_v   = d_in[29];
  const void* mlp_g   = d_in[30];
  const void* mlp_b   = d_in[31];
  const void* ln_f_g  = d_in[32];
  const void* ln_f_b  = d_in[33];
  const void* W_lm    = d_in[34];

  // workspace carve
  char* p = (char*)d_ws;
  auto alloc = [&](size_t bytes) { char* r = p; p += (bytes + 255) & ~(size_t)255; return r; };
  float* h      = (float*)alloc((size_t)NTOK * EMB * 4);
  bf16*  x_bf   = (bf16*) alloc((size_t)NTOK * EMB * 2);
  float* qkv    = (float*)alloc((size_t)NTOK * 3 * EMB * 4);
  bf16*  o_bf   = (bf16*) alloc((size_t)NTOK * EMB * 2);
  bf16*  act_bf = (bf16*) alloc((size_t)NTOK * FF * 2);
  float* cond   = (float*)alloc((size_t)BB * EMB * 4);
  float* sc_att = (float*)alloc((size_t)NL * EMB * 4);
  float* sc_mlp = (float*)alloc((size_t)NL * FF * 4);
  int*   dflag  = (int*)  alloc(256);
  bf16*  Wt_qkv = (bf16*) alloc((size_t)(3 * EMB) * EMB * 2);   // [2304][768]
  bf16*  Wt_att = (bf16*) alloc((size_t)EMB * EMB * 2);         // [768][768]
  bf16*  Wt_fc  = (bf16*) alloc((size_t)FF * EMB * 2);          // [3072][768]
  bf16*  Wt_mlp = (bf16*) alloc((size_t)EMB * FF * 2);          // [768][3072]
  bf16*  Wt_lm  = (bf16*) alloc((size_t)VOC * EMB * 2);         // [50257][768]

  // dtype detect (ln1_g is all-ones in either dtype)
  detect_kernel<<<1, 64, 0, stream>>>((const unsigned*)ln1_g, dflag);

  // precompute
  wn_scale_kernel<<<NL * EMB, 64, 0, stream>>>(attn_v, attn_g, sc_att, EMB, dflag);
  wn_scale_kernel<<<NL * FF,  64, 0, stream>>>(mlp_v,  mlp_g,  sc_mlp, EMB, dflag);
  cond_kernel<<<BB, EMB, 0, stream>>>(emotion_ids, context_ids, personality_ids,
                                      emo_emb, ctx_emb, pers_emb,
                                      W_emo, b_emo, W_ctx, b_ctx, W_pers, b_pers, cond, dflag);
  embed_kernel<<<(NTOK * EMB) / 256, 256, 0, stream>>>(input_ids, position_ids, wte, wpe, cond, h, dflag);

  // LM head weight: transpose+cast once per launch
  convT_kernel<<<dim3((VOC + 31) / 32, EMB / 32), 256, 0, stream>>>(
      W_lm, 0, nullptr, Wt_lm, EMB, VOC, dflag);

  const int num_m = NTOK / 128;   // 16
  for (int l = 0; l < NL; ++l) {
    size_t off_E   = (size_t)l * EMB;
    size_t off_3E  = (size_t)l * 3 * EMB;
    size_t off_EE  = (size_t)l * EMB * EMB;
    size_t off_E3E = (size_t)l * EMB * 3 * EMB;
    size_t off_EI  = (size_t)l * EMB * FF;
    size_t off_I   = (size_t)l * FF;
    size_t off_IE  = (size_t)l * FF * EMB;
    size_t off_H   = (size_t)l * NH;

    // per-layer weight convert (transpose to [N][K] bf16; fold wn scale for attn/mlp proj)
    convT_kernel<<<dim3((3 * EMB) / 32, EMB / 32), 256, 0, stream>>>(
        W_qkv, off_E3E, nullptr, Wt_qkv, EMB, 3 * EMB, dflag);
    convT_kernel<<<dim3(EMB / 32, EMB / 32), 256, 0, stream>>>(
        attn_v, off_EE, sc_att + l * EMB, Wt_att, EMB, EMB, dflag);
    convT_kernel<<<dim3(FF / 32, EMB / 32), 256, 0, stream>>>(
        W_fc, off_EI, nullptr, Wt_fc, EMB, FF, dflag);
    convT_kernel<<<dim3(EMB / 32, FF / 32), 256, 0, stream>>>(
        mlp_v, off_IE, sc_mlp + l * FF, Wt_mlp, FF, EMB, dflag);

    ln_kernel<<<NTOK, 256, 0, stream>>>(h, ln1_g, ln1_b, off_E, x_bf, dflag);
    gemm128_kernel<EPI_F32><<<num_m * 18, 256, 0, stream>>>(
        x_bf, Wt_qkv, b_qkv, off_3E, qkv, NTOK, 3 * EMB, EMB, 18, num_m, dflag);
    fattn_kernel<<<dim3(SEQ / 64, NH, BB), 256, 0, stream>>>(qkv, emo_bias, off_H, mask, o_bf, dflag);
    gemm128_kernel<EPI_ADD><<<num_m * 6, 256, 0, stream>>>(
        o_bf, Wt_att, attn_b, off_E, h, NTOK, EMB, EMB, 6, num_m, dflag);
    ln_kernel<<<NTOK, 256, 0, stream>>>(h, ln2_g, ln2_b, off_E, x_bf, dflag);
    gemm128_kernel<EPI_GELU><<<num_m * 24, 256, 0, stream>>>(
        x_bf, Wt_fc, b_fc, off_I, act_bf, NTOK, FF, EMB, 24, num_m, dflag);
    gemm128_kernel<EPI_ADD><<<num_m * 6, 256, 0, stream>>>(
        act_bf, Wt_mlp, mlp_b, off_E, h, NTOK, EMB, FF, 6, num_m, dflag);
  }

  ln_kernel<<<NTOK, 256, 0, stream>>>(h, ln_f_g, ln_f_b, 0, x_bf, dflag);
  const int lm_nn = (VOC + 127) / 128;   // 393
  gemm128_kernel<EPI_OUT><<<num_m * lm_nn, 256, 0, stream>>>(
      x_bf, Wt_lm, nullptr, 0, d_out, NTOK, VOC, EMB, lm_nn, num_m, dflag);
}